// Round 8
// baseline (264.371 us; speedup 1.0000x reference)
//
#include <hip/hip_runtime.h>

#define TLEN 512
#define XSTR 516      // x LDS row stride (floats)
#define HSTR 40       // h LDS row stride (bf16 elems): 80B rows, 16B-aligned frags

typedef __attribute__((ext_vector_type(8))) short bf16x8;
typedef __attribute__((ext_vector_type(4))) float f32x4;

#define LOG2E_ 1.44269504f
#define S2F_   2.88539008f   // 2*log2e; c kept in S2F*c space

__device__ __forceinline__ float fexp2_(float x) {
#if __has_builtin(__builtin_amdgcn_exp2f)
    return __builtin_amdgcn_exp2f(x);      // raw v_exp_f32
#else
    return __expf(x * 0.69314718056f);
#endif
}
__device__ __forceinline__ float frcp_(float x) {
#if __has_builtin(__builtin_amdgcn_rcpf)
    return __builtin_amdgcn_rcpf(x);       // raw v_rcp_f32 (~1 ulp)
#else
    return 1.0f / x;
#endif
}
__device__ __forceinline__ unsigned short f2bf(float f) {   // RNE (setup only)
    unsigned u = __float_as_uint(f);
    u += 0x7FFFu + ((u >> 16) & 1u);
    return (unsigned short)(u >> 16);
}
__device__ __forceinline__ float bf2f(unsigned short b) {
    return __uint_as_float(((unsigned)b) << 16);
}

// Gate pre-activations arrive PRE-SCALED (folded into weights/biases):
//  sigmoid rows (i,f,o): a = -log2e * x  -> sig = rcp(1+exp2(a))
//  tanh row    (g):      a = 2log2e * x  -> S2F*tanh = S2F - 2*S2F*rcp(1+exp2(a))
// c kept in S2F*c space -> tanh(c) = 1 - 2*rcp(1+exp2(c')).
__device__ __forceinline__ float lstm_nl(const f32x4 a, float& cS) {
    const float i_ = frcp_(1.0f + fexp2_(a[0]));
    const float f_ = frcp_(1.0f + fexp2_(a[1]));
    const float rg = frcp_(1.0f + fexp2_(a[2]));
    const float g_ = S2F_ - 2.0f * S2F_ * rg;      // S2F*tanh(g)
    const float o_ = frcp_(1.0f + fexp2_(a[3]));
    cS = f_ * cS + i_ * g_;
    const float rc = frcp_(1.0f + fexp2_(cS));
    return o_ * (1.0f - 2.0f * rc);
}

// Block = 16 batch cols, 16 waves (1024 thr), 4 waves/SIMD.
//  wave w in [0,8):  L0 tile w   -> 3 MFMAs + 1 NL/lane
//  wave 8+w:         L1 tile w   -> 6 MFMAs (two parallel 3-chains) + 1 NL/lane
// (R7 had 8 waves x (9 MFMA + 2 NL); wall was per-wave chain latency with only
//  2 waves/SIMD to overlap. Halve the chain, double the waves.)
// MIXED-GATE tiles: tile-row = 4*jj + gate; weight row = gate*32+4*tile+jj.
// Lane (col=lane&15, kq=lane>>4): D rows kq*4+r = all 4 gates of j=4*tile+kq.
// fp32 accuracy: bf16 hi/lo split, 3 MFMAs per matvec.
// L1 lags L0 by one step; all reads hit prev-parity buffers -> 1 barrier/step.
__global__ __launch_bounds__(1024, 1)
void lstm2_mfma(const float* __restrict__ x,
                const float* __restrict__ w_ih0,
                const float* __restrict__ w_hh0,
                const float* __restrict__ b_ih0,
                const float* __restrict__ b_hh0,
                const float* __restrict__ w_ih1,
                const float* __restrict__ w_hh1,
                const float* __restrict__ b_ih1,
                const float* __restrict__ b_hh1,
                const float* __restrict__ fc1_w,
                const float* __restrict__ fc1_b,
                const float* __restrict__ fc2_w,
                const float* __restrict__ fc2_b,
                float* __restrict__ out)
{
    __shared__ float x_lds[16][XSTR];
    __shared__ unsigned short h0b[2][2][16][HSTR];  // [dbuf][hi/lo][b][k]
    __shared__ unsigned short h1b[2][2][16][HSTR];
    __shared__ float h1f[16][36];                   // final h1 (f32) for head

    const int tid  = threadIdx.x;
    const int wid  = tid >> 6;
    const int lane = tid & 63;
    const int col  = lane & 15;   // batch col
    const int kq   = lane >> 4;
    const int b0   = blockIdx.x * 16;

    // ---- stage x (coalesced float4) ----
    for (int i4 = tid; i4 < (16 * TLEN) / 4; i4 += 1024) {
        const int idx = i4 * 4;
        const int row = idx >> 9, cx = idx & 511;
        float4 v = *(const float4*)(x + (long)(b0 + row) * TLEN + cx);
        *(float4*)&x_lds[row][cx] = v;
    }
    for (int i = tid; i < 2 * 2 * 16 * HSTR; i += 1024) {
        ((unsigned short*)h0b)[i] = 0;
        ((unsigned short*)h1b)[i] = 0;
    }

    const bool L0w  = (wid < 8);
    const int  tile = wid & 7;
    const int  jj   = 4 * tile + kq;    // this lane's j
    const int  k0   = kq * 8;

    // A-frag weight row (mixed-gate tile ordering); per-row exp2 pre-scale
    const int   arow = (col & 3) * 32 + 4 * tile + (col >> 2);
    const float sA   = ((col & 3) == 2) ? S2F_ : -LOG2E_;

    // L0 waves: wL0 = w_hh0.  L1 waves: wI = w_ih1, wH = w_hh1.
    bf16x8 wAhi, wAlo, wHhi, wHlo;
    {
        const float* WA = L0w ? w_hh0 : w_ih1;
        #pragma unroll
        for (int e = 0; e < 8; ++e) {
            float w;
            unsigned short hb;
            w = sA * WA[arow * 32 + k0 + e]; hb = f2bf(w);
            wAhi[e] = (short)hb; wAlo[e] = (short)f2bf(w - bf2f(hb));
            w = L0w ? 0.0f : sA * w_hh1[arow * 32 + k0 + e]; hb = f2bf(w);
            wHhi[e] = (short)hb; wHlo[e] = (short)f2bf(w - bf2f(hb));
        }
    }

    // bias / x-weight for this lane's D rows: row(r) = r*32 + 4*tile + kq
    f32x4 biasv, xwv;
    #pragma unroll
    for (int r = 0; r < 4; ++r) {
        const int  row = r * 32 + 4 * tile + kq;
        const float sr = (r == 2) ? S2F_ : -LOG2E_;
        biasv[r] = L0w ? sr * (b_ih0[row] + b_hh0[row])
                       : sr * (b_ih1[row] + b_hh1[row]);
        xwv[r]   = L0w ? sr * w_ih0[row] : 0.0f;
    }

    float cS = 0.0f;      // cell state (S2F-scaled), one j per lane
    __syncthreads();

#define PACK_H(BUF, PAR, HV, J)                                                  \
    do {                                                                         \
        const unsigned u_ = __float_as_uint(HV);                                 \
        BUF[PAR][0][col][J] = (unsigned short)(u_ >> 16);                        \
        const float lof_ = (HV) - __uint_as_float(u_ & 0xFFFF0000u);             \
        BUF[PAR][1][col][J] = (unsigned short)(__float_as_uint(lof_) >> 16);     \
    } while (0)

// One timestep; CUR/PRV compile-time -> LDS addrs fold to base+immediate.
#define STEP_BODY(T, CUR, PRV)                                                   \
    do {                                                                         \
        const int t_ = (T);                                                      \
        if (L0w) {                                                               \
            if (t_ < TLEN) {                                                     \
                const bf16x8 bhi = *(const bf16x8*)&h0b[PRV][0][col][k0];        \
                const bf16x8 blo = *(const bf16x8*)&h0b[PRV][1][col][k0];        \
                const float xt = x_lds[col][t_];                                 \
                f32x4 a = biasv + xwv * xt;                                      \
                a = __builtin_amdgcn_mfma_f32_16x16x32_bf16(wAhi, bhi, a, 0, 0, 0); \
                a = __builtin_amdgcn_mfma_f32_16x16x32_bf16(wAhi, blo, a, 0, 0, 0); \
                a = __builtin_amdgcn_mfma_f32_16x16x32_bf16(wAlo, bhi, a, 0, 0, 0); \
                const float hv = lstm_nl(a, cS);                                 \
                PACK_H(h0b, CUR, hv, jj);                                        \
            }                                                                    \
        } else {                                                                 \
            if (t_ >= 1) {                                                       \
                const bf16x8 bhi = *(const bf16x8*)&h0b[PRV][0][col][k0];        \
                const bf16x8 blo = *(const bf16x8*)&h0b[PRV][1][col][k0];        \
                const bf16x8 chi = *(const bf16x8*)&h1b[CUR][0][col][k0];        \
                const bf16x8 clo = *(const bf16x8*)&h1b[CUR][1][col][k0];        \
                f32x4 aI = biasv;                                                \
                f32x4 aH = {0.0f, 0.0f, 0.0f, 0.0f};                             \
                aI = __builtin_amdgcn_mfma_f32_16x16x32_bf16(wAhi, bhi, aI, 0, 0, 0); \
                aH = __builtin_amdgcn_mfma_f32_16x16x32_bf16(wHhi, chi, aH, 0, 0, 0); \
                aI = __builtin_amdgcn_mfma_f32_16x16x32_bf16(wAhi, blo, aI, 0, 0, 0); \
                aH = __builtin_amdgcn_mfma_f32_16x16x32_bf16(wHhi, clo, aH, 0, 0, 0); \
                aI = __builtin_amdgcn_mfma_f32_16x16x32_bf16(wAlo, bhi, aI, 0, 0, 0); \
                aH = __builtin_amdgcn_mfma_f32_16x16x32_bf16(wHlo, chi, aH, 0, 0, 0); \
                const f32x4 a = aI + aH;                                         \
                const float hv = lstm_nl(a, cS);                                 \
                PACK_H(h1b, PRV, hv, jj);                                        \
                if (t_ == TLEN) h1f[col][jj] = hv;                               \
            }                                                                    \
        }                                                                        \
        __syncthreads();                                                         \
    } while (0)

    STEP_BODY(0, 0, 1);
    for (int tt = 1; tt < TLEN; tt += 2) {
        STEP_BODY(tt,     1, 0);
        STEP_BODY(tt + 1, 0, 1);
    }
#undef STEP_BODY
#undef PACK_H

    // ---- head: out[b] = fc2( relu( fc1 . h1_T ) ) + fc2_b, by wave 0 ----
    if (wid == 0) {
        float s = 0.0f;
        #pragma unroll
        for (int it = 0; it < 4; ++it) {
            const int r = kq * 4 + it;    // fc1 row in [0,16)
            float acc = fc1_b[r];
            #pragma unroll
            for (int qq = 0; qq < 8; ++qq) {
                const float4 wv = *(const float4*)(fc1_w + r * 32 + qq * 4);
                const float4 hv = *(const float4*)&h1f[col][qq * 4];
                acc += wv.x * hv.x + wv.y * hv.y + wv.z * hv.z + wv.w * hv.w;
            }
            s += fmaxf(acc, 0.0f) * fc2_w[r];
        }
        s += __shfl_xor(s, 16);
        s += __shfl_xor(s, 32);
        if (lane < 16) out[b0 + col] = s + fc2_b[0];
    }
}

extern "C" void kernel_launch(void* const* d_in, const int* in_sizes, int n_in,
                              void* d_out, int out_size, void* d_ws, size_t ws_size,
                              hipStream_t stream) {
    const float* x     = (const float*)d_in[0];
    const float* w_ih0 = (const float*)d_in[1];
    const float* w_hh0 = (const float*)d_in[2];
    const float* b_ih0 = (const float*)d_in[3];
    const float* b_hh0 = (const float*)d_in[4];
    const float* w_ih1 = (const float*)d_in[5];
    const float* w_hh1 = (const float*)d_in[6];
    const float* b_ih1 = (const float*)d_in[7];
    const float* b_hh1 = (const float*)d_in[8];
    const float* fc1_w = (const float*)d_in[9];
    const float* fc1_b = (const float*)d_in[10];
    const float* fc2_w = (const float*)d_in[11];
    const float* fc2_b = (const float*)d_in[12];
    float* out = (float*)d_out;

    dim3 grid(4096 / 16);   // 256 blocks, 1 per CU
    dim3 block(1024);       // 16 waves -> 4 per SIMD
    hipLaunchKernelGGL(lstm2_mfma, grid, block, 0, stream,
                       x, w_ih0, w_hh0, b_ih0, b_hh0,
                       w_ih1, w_hh1, b_ih1, b_hh1,
                       fc1_w, fc1_b, fc2_w, fc2_b, out);
}